// Round 1
// baseline (2861.128 us; speedup 1.0000x reference)
//
#include <hip/hip_runtime.h>
#include <cstddef>

#define NN 50000
#define DD 128
#define BN_EPS 1e-5f
#define SLOPE 0.01f

// ---------------- Kernel A: edge scatter-sum aggregation ----------------
// 32 threads per edge, each handles 4 features (float4 gather, 4 atomics).
__global__ void scatter_kernel(const float* __restrict__ h,
                               const int* __restrict__ src,
                               const int* __restrict__ dst,
                               float* __restrict__ agg, int E) {
    long long tid = (long long)blockIdx.x * blockDim.x + threadIdx.x;
    int e = (int)(tid >> 5);
    int lane = (int)(tid & 31);
    if (e >= E) return;
    int s = src[e];
    int d = dst[e];
    float4 v = ((const float4*)(h + (size_t)s * DD))[lane];
    float* ap = agg + (size_t)d * DD + lane * 4;
    atomicAdd(ap + 0, v.x);
    atomicAdd(ap + 1, v.y);
    atomicAdd(ap + 2, v.z);
    atomicAdd(ap + 3, v.w);
}

// ---------------- GEMM: out[n,128] = act(A[n,128] @ W[128,128] + bias) ----
// FUSE_IN: A = epsval * A0 + A1 (computed while staging tile)
// RELU: apply relu to output
// STATS: accumulate column sum / sumsq of output into stats[0..127],[128..255]
template <bool FUSE_IN, bool RELU, bool STATS>
__global__ __launch_bounds__(256) void gemm_kernel(
        const float* __restrict__ A0, const float* __restrict__ A1,
        const float* __restrict__ eps_ptr,
        const float* __restrict__ W, const float* __restrict__ bias,
        float* __restrict__ out, float* __restrict__ stats, int n) {
    __shared__ float As[64][36];     // +4 pad keeps float4 stores 16B-aligned
    __shared__ float Ws[32][128];
    __shared__ float Ssum[128];
    __shared__ float Ssq[128];

    const int t = threadIdx.x;
    const int cg = t & 31;   // column group: 4 cols
    const int rg = t >> 5;   // row group: 8 rows
    const int row0 = blockIdx.x * 64;

    float epsval = 1.0f;
    if (FUSE_IN) epsval = 1.0f + *eps_ptr;

    if (STATS) {
        if (t < 128) { Ssum[t] = 0.0f; Ssq[t] = 0.0f; }
    }

    float acc[8][4];
#pragma unroll
    for (int i = 0; i < 8; ++i)
#pragma unroll
        for (int j = 0; j < 4; ++j) acc[i][j] = 0.0f;

    for (int k0 = 0; k0 < 128; k0 += 32) {
        // stage A tile: 64 rows x 32 cols = 512 float4s, 2 per thread
#pragma unroll
        for (int jj = 0; jj < 2; ++jj) {
            int j = t + jj * 256;
            int r = j >> 3;
            int c4 = j & 7;
            int row = row0 + r;
            float4 v = make_float4(0.f, 0.f, 0.f, 0.f);
            if (row < n) {
                v = *((const float4*)(A0 + (size_t)row * DD + k0) + c4);
                if (FUSE_IN) {
                    float4 u = *((const float4*)(A1 + (size_t)row * DD + k0) + c4);
                    v.x = epsval * v.x + u.x;
                    v.y = epsval * v.y + u.y;
                    v.z = epsval * v.z + u.z;
                    v.w = epsval * v.w + u.w;
                }
            }
            *(float4*)&As[r][c4 * 4] = v;
        }
        // stage W tile: 32 rows x 128 cols = 1024 float4s, 4 per thread
#pragma unroll
        for (int jj = 0; jj < 4; ++jj) {
            int j = t + jj * 256;
            int r = j >> 5;
            int c4 = j & 31;
            *(float4*)&Ws[r][c4 * 4] = *((const float4*)(W + (size_t)(k0 + r) * DD) + c4);
        }
        __syncthreads();
#pragma unroll
        for (int kk = 0; kk < 32; ++kk) {
            float4 w = *(float4*)&Ws[kk][cg * 4];
#pragma unroll
            for (int i = 0; i < 8; ++i) {
                float a = As[rg * 8 + i][kk];
                acc[i][0] = fmaf(a, w.x, acc[i][0]);
                acc[i][1] = fmaf(a, w.y, acc[i][1]);
                acc[i][2] = fmaf(a, w.z, acc[i][2]);
                acc[i][3] = fmaf(a, w.w, acc[i][3]);
            }
        }
        __syncthreads();
    }

    const float4 bv = *((const float4*)bias + cg);
    float psum[4] = {0.f, 0.f, 0.f, 0.f};
    float psq[4] = {0.f, 0.f, 0.f, 0.f};
#pragma unroll
    for (int i = 0; i < 8; ++i) {
        int row = row0 + rg * 8 + i;
        float4 o;
        o.x = acc[i][0] + bv.x;
        o.y = acc[i][1] + bv.y;
        o.z = acc[i][2] + bv.z;
        o.w = acc[i][3] + bv.w;
        if (RELU) {
            o.x = fmaxf(o.x, 0.f); o.y = fmaxf(o.y, 0.f);
            o.z = fmaxf(o.z, 0.f); o.w = fmaxf(o.w, 0.f);
        }
        if (row < n) {
            *(float4*)(out + (size_t)row * DD + cg * 4) = o;
            if (STATS) {
                psum[0] += o.x; psum[1] += o.y; psum[2] += o.z; psum[3] += o.w;
                psq[0] += o.x * o.x; psq[1] += o.y * o.y;
                psq[2] += o.z * o.z; psq[3] += o.w * o.w;
            }
        }
    }
    if (STATS) {
        __syncthreads();  // Ssum init visible
        atomicAdd(&Ssum[cg * 4 + 0], psum[0]);
        atomicAdd(&Ssum[cg * 4 + 1], psum[1]);
        atomicAdd(&Ssum[cg * 4 + 2], psum[2]);
        atomicAdd(&Ssum[cg * 4 + 3], psum[3]);
        atomicAdd(&Ssq[cg * 4 + 0], psq[0]);
        atomicAdd(&Ssq[cg * 4 + 1], psq[1]);
        atomicAdd(&Ssq[cg * 4 + 2], psq[2]);
        atomicAdd(&Ssq[cg * 4 + 3], psq[3]);
        __syncthreads();
        if (t < 128) {
            atomicAdd(&stats[t], Ssum[t]);
            atomicAdd(&stats[128 + t], Ssq[t]);
        }
    }
}

// ---------------- BN finalize: per-column scale/shift ----------------
__global__ void bn_finalize(const float* __restrict__ stats,
                            const float* __restrict__ gamma,
                            const float* __restrict__ beta,
                            float* __restrict__ scsh, int n) {
    int c = threadIdx.x;
    float inv_n = 1.0f / (float)n;
    float mean = stats[c] * inv_n;
    float var = stats[128 + c] * inv_n - mean * mean;
    float sc = gamma[c] * rsqrtf(var + BN_EPS);
    scsh[c] = sc;
    scsh[128 + c] = beta[c] - mean * sc;
}

// ---------------- apply: out = h + leaky(z2*scale + shift) ----------------
__global__ void apply_kernel(const float* __restrict__ h,
                             const float* __restrict__ z2,
                             const float* __restrict__ scsh,
                             float* __restrict__ out, int total4) {
    int i = blockIdx.x * blockDim.x + threadIdx.x;
    if (i >= total4) return;
    int c4 = i & 31;  // float4-index within the 128-wide row
    float4 sc = ((const float4*)scsh)[c4];
    float4 sh = ((const float4*)(scsh + 128))[c4];
    float4 z = ((const float4*)z2)[i];
    float4 hh = ((const float4*)h)[i];
    float4 o;
    float v;
    v = fmaf(z.x, sc.x, sh.x); o.x = hh.x + (v >= 0.f ? v : SLOPE * v);
    v = fmaf(z.y, sc.y, sh.y); o.y = hh.y + (v >= 0.f ? v : SLOPE * v);
    v = fmaf(z.z, sc.z, sh.z); o.z = hh.z + (v >= 0.f ? v : SLOPE * v);
    v = fmaf(z.w, sc.w, sh.w); o.w = hh.w + (v >= 0.f ? v : SLOPE * v);
    ((float4*)out)[i] = o;
}

extern "C" void kernel_launch(void* const* d_in, const int* in_sizes, int n_in,
                              void* d_out, int out_size, void* d_ws, size_t ws_size,
                              hipStream_t stream) {
    const float* h     = (const float*)d_in[0];
    const int*   src   = (const int*)d_in[1];
    const int*   dst   = (const int*)d_in[2];
    const float* eps   = (const float*)d_in[3];
    const float* W1    = (const float*)d_in[4];
    const float* b1    = (const float*)d_in[5];
    const float* W2    = (const float*)d_in[6];
    const float* b2    = (const float*)d_in[7];
    const float* gamma = (const float*)d_in[8];
    const float* beta  = (const float*)d_in[9];
    float* out = (float*)d_out;

    const int n = in_sizes[0] / DD;   // 50000
    const int E = in_sizes[1];        // 1600000

    // workspace layout (floats)
    float* ws   = (float*)d_ws;
    float* agg  = ws;                       // n*DD  (reused as z2)
    float* z1   = ws + (size_t)n * DD;      // n*DD
    float* stats = ws + (size_t)2 * n * DD; // 256: col sum, col sumsq
    float* scsh  = stats + 256;             // 256: scale, shift
    float* z2   = agg;                      // reuse after GEMM1 consumed agg

    hipMemsetAsync(agg, 0, (size_t)n * DD * sizeof(float), stream);
    hipMemsetAsync(stats, 0, 256 * sizeof(float), stream);

    {   // scatter
        long long threads = (long long)E * 32;
        int blocks = (int)((threads + 255) / 256);
        scatter_kernel<<<blocks, 256, 0, stream>>>(h, src, dst, agg, E);
    }
    {   // GEMM1: z1 = relu(((1+eps)h + agg) @ W1 + b1)
        int blocks = (n + 63) / 64;
        gemm_kernel<true, true, false><<<blocks, 256, 0, stream>>>(
            h, agg, eps, W1, b1, z1, nullptr, n);
    }
    {   // GEMM2: z2 = z1 @ W2 + b2, with BN stats
        int blocks = (n + 63) / 64;
        gemm_kernel<false, false, true><<<blocks, 256, 0, stream>>>(
            z1, nullptr, nullptr, W2, b2, z2, stats, n);
    }
    bn_finalize<<<1, 128, 0, stream>>>(stats, gamma, beta, scsh, n);
    {   // apply BN + leaky relu + residual
        int total4 = n * DD / 4;
        int blocks = (total4 + 255) / 256;
        apply_kernel<<<blocks, 256, 0, stream>>>(h, z2, scsh, out, total4);
    }
}

// Round 2
// 582.593 us; speedup vs baseline: 4.9110x; 4.9110x over previous
//
#include <hip/hip_runtime.h>
#include <cstddef>

#define DD 128
#define BN_EPS 1e-5f
#define SLOPE 0.01f

// ---------- CSR build step 1: degree histogram ----------
__global__ void hist_kernel(const int* __restrict__ dst, int* __restrict__ deg, int E) {
    int e = blockIdx.x * blockDim.x + threadIdx.x;
    if (e >= E) return;
    atomicAdd(&deg[dst[e]], 1);
}

// ---------- CSR build step 2: exclusive scan of degrees (single block) ----------
__global__ __launch_bounds__(1024) void scan_kernel(const int* __restrict__ deg,
                                                    int* __restrict__ off,
                                                    int* __restrict__ cursor, int n) {
    __shared__ int sums[1024];
    const int t = threadIdx.x;
    const int per = (n + 1023) / 1024;
    const int start = t * per;
    const int end = min(start + per, n);
    int s = 0;
    for (int i = start; i < end; ++i) s += deg[i];
    sums[t] = s;
    __syncthreads();
    // Hillis-Steele inclusive scan
    for (int d = 1; d < 1024; d <<= 1) {
        int v = (t >= d) ? sums[t - d] : 0;
        __syncthreads();
        sums[t] += v;
        __syncthreads();
    }
    int base = (t == 0) ? 0 : sums[t - 1];
    for (int i = start; i < end; ++i) {
        off[i] = base;
        cursor[i] = base;
        base += deg[i];
    }
    if (t == 0) off[n] = sums[1023];
}

// ---------- CSR build step 3: fill sorted src ids ----------
__global__ void fill_kernel(const int* __restrict__ src, const int* __restrict__ dst,
                            int* __restrict__ cursor, int* __restrict__ ssrc, int E) {
    int e = blockIdx.x * blockDim.x + threadIdx.x;
    if (e >= E) return;
    int pos = atomicAdd(&cursor[dst[e]], 1);
    ssrc[pos] = src[e];
}

// ---------- gather: agg[u] = sum_{s in N_in(u)} h[s], no atomics ----------
__global__ __launch_bounds__(256) void gather_kernel(const float* __restrict__ h,
                                                     const int* __restrict__ off,
                                                     const int* __restrict__ ssrc,
                                                     float* __restrict__ agg, int n) {
    const int u = blockIdx.x * 8 + (threadIdx.x >> 5);
    const int lane = threadIdx.x & 31;
    if (u >= n) return;
    int b = off[u];
    const int e = off[u + 1];
    float4 acc = make_float4(0.f, 0.f, 0.f, 0.f);
    // unroll-2 with index prefetch to break the dependent-load chain a bit
    for (; b + 2 <= e; b += 2) {
        int s0 = ssrc[b];
        int s1 = ssrc[b + 1];
        float4 v0 = ((const float4*)(h + (size_t)s0 * DD))[lane];
        float4 v1 = ((const float4*)(h + (size_t)s1 * DD))[lane];
        acc.x += v0.x + v1.x;
        acc.y += v0.y + v1.y;
        acc.z += v0.z + v1.z;
        acc.w += v0.w + v1.w;
    }
    if (b < e) {
        int s0 = ssrc[b];
        float4 v0 = ((const float4*)(h + (size_t)s0 * DD))[lane];
        acc.x += v0.x; acc.y += v0.y; acc.z += v0.z; acc.w += v0.w;
    }
    ((float4*)(agg + (size_t)u * DD))[lane] = acc;
}

// ---------------- GEMM: out[n,128] = act(A[n,128] @ W[128,128] + bias) ----
template <bool FUSE_IN, bool RELU, bool STATS>
__global__ __launch_bounds__(256) void gemm_kernel(
        const float* __restrict__ A0, const float* __restrict__ A1,
        const float* __restrict__ eps_ptr,
        const float* __restrict__ W, const float* __restrict__ bias,
        float* __restrict__ out, float* __restrict__ stats, int n) {
    __shared__ float As[64][36];
    __shared__ float Ws[32][128];
    __shared__ float Ssum[128];
    __shared__ float Ssq[128];

    const int t = threadIdx.x;
    const int cg = t & 31;
    const int rg = t >> 5;
    const int row0 = blockIdx.x * 64;

    float epsval = 1.0f;
    if (FUSE_IN) epsval = 1.0f + *eps_ptr;

    if (STATS) {
        if (t < 128) { Ssum[t] = 0.0f; Ssq[t] = 0.0f; }
    }

    float acc[8][4];
#pragma unroll
    for (int i = 0; i < 8; ++i)
#pragma unroll
        for (int j = 0; j < 4; ++j) acc[i][j] = 0.0f;

    for (int k0 = 0; k0 < 128; k0 += 32) {
#pragma unroll
        for (int jj = 0; jj < 2; ++jj) {
            int j = t + jj * 256;
            int r = j >> 3;
            int c4 = j & 7;
            int row = row0 + r;
            float4 v = make_float4(0.f, 0.f, 0.f, 0.f);
            if (row < n) {
                v = *((const float4*)(A0 + (size_t)row * DD + k0) + c4);
                if (FUSE_IN) {
                    float4 u = *((const float4*)(A1 + (size_t)row * DD + k0) + c4);
                    v.x = epsval * v.x + u.x;
                    v.y = epsval * v.y + u.y;
                    v.z = epsval * v.z + u.z;
                    v.w = epsval * v.w + u.w;
                }
            }
            *(float4*)&As[r][c4 * 4] = v;
        }
#pragma unroll
        for (int jj = 0; jj < 4; ++jj) {
            int j = t + jj * 256;
            int r = j >> 5;
            int c4 = j & 31;
            *(float4*)&Ws[r][c4 * 4] = *((const float4*)(W + (size_t)(k0 + r) * DD) + c4);
        }
        __syncthreads();
#pragma unroll
        for (int kk = 0; kk < 32; ++kk) {
            float4 w = *(float4*)&Ws[kk][cg * 4];
#pragma unroll
            for (int i = 0; i < 8; ++i) {
                float a = As[rg * 8 + i][kk];
                acc[i][0] = fmaf(a, w.x, acc[i][0]);
                acc[i][1] = fmaf(a, w.y, acc[i][1]);
                acc[i][2] = fmaf(a, w.z, acc[i][2]);
                acc[i][3] = fmaf(a, w.w, acc[i][3]);
            }
        }
        __syncthreads();
    }

    const float4 bv = *((const float4*)bias + cg);
    float psum[4] = {0.f, 0.f, 0.f, 0.f};
    float psq[4] = {0.f, 0.f, 0.f, 0.f};
#pragma unroll
    for (int i = 0; i < 8; ++i) {
        int row = row0 + rg * 8 + i;
        float4 o;
        o.x = acc[i][0] + bv.x;
        o.y = acc[i][1] + bv.y;
        o.z = acc[i][2] + bv.z;
        o.w = acc[i][3] + bv.w;
        if (RELU) {
            o.x = fmaxf(o.x, 0.f); o.y = fmaxf(o.y, 0.f);
            o.z = fmaxf(o.z, 0.f); o.w = fmaxf(o.w, 0.f);
        }
        if (row < n) {
            *(float4*)(out + (size_t)row * DD + cg * 4) = o;
            if (STATS) {
                psum[0] += o.x; psum[1] += o.y; psum[2] += o.z; psum[3] += o.w;
                psq[0] += o.x * o.x; psq[1] += o.y * o.y;
                psq[2] += o.z * o.z; psq[3] += o.w * o.w;
            }
        }
    }
    if (STATS) {
        __syncthreads();
        atomicAdd(&Ssum[cg * 4 + 0], psum[0]);
        atomicAdd(&Ssum[cg * 4 + 1], psum[1]);
        atomicAdd(&Ssum[cg * 4 + 2], psum[2]);
        atomicAdd(&Ssum[cg * 4 + 3], psum[3]);
        atomicAdd(&Ssq[cg * 4 + 0], psq[0]);
        atomicAdd(&Ssq[cg * 4 + 1], psq[1]);
        atomicAdd(&Ssq[cg * 4 + 2], psq[2]);
        atomicAdd(&Ssq[cg * 4 + 3], psq[3]);
        __syncthreads();
        if (t < 128) {
            atomicAdd(&stats[t], Ssum[t]);
            atomicAdd(&stats[128 + t], Ssq[t]);
        }
    }
}

// ---------------- BN finalize ----------------
__global__ void bn_finalize(const float* __restrict__ stats,
                            const float* __restrict__ gamma,
                            const float* __restrict__ beta,
                            float* __restrict__ scsh, int n) {
    int c = threadIdx.x;
    float inv_n = 1.0f / (float)n;
    float mean = stats[c] * inv_n;
    float var = stats[128 + c] * inv_n - mean * mean;
    float sc = gamma[c] * rsqrtf(var + BN_EPS);
    scsh[c] = sc;
    scsh[128 + c] = beta[c] - mean * sc;
}

// ---------------- apply: out = h + leaky(z2*scale + shift) ----------------
__global__ void apply_kernel(const float* __restrict__ h,
                             const float* __restrict__ z2,
                             const float* __restrict__ scsh,
                             float* __restrict__ out, int total4) {
    int i = blockIdx.x * blockDim.x + threadIdx.x;
    if (i >= total4) return;
    int c4 = i & 31;
    float4 sc = ((const float4*)scsh)[c4];
    float4 sh = ((const float4*)(scsh + 128))[c4];
    float4 z = ((const float4*)z2)[i];
    float4 hh = ((const float4*)h)[i];
    float4 o;
    float v;
    v = fmaf(z.x, sc.x, sh.x); o.x = hh.x + (v >= 0.f ? v : SLOPE * v);
    v = fmaf(z.y, sc.y, sh.y); o.y = hh.y + (v >= 0.f ? v : SLOPE * v);
    v = fmaf(z.z, sc.z, sh.z); o.z = hh.z + (v >= 0.f ? v : SLOPE * v);
    v = fmaf(z.w, sc.w, sh.w); o.w = hh.w + (v >= 0.f ? v : SLOPE * v);
    ((float4*)out)[i] = o;
}

extern "C" void kernel_launch(void* const* d_in, const int* in_sizes, int n_in,
                              void* d_out, int out_size, void* d_ws, size_t ws_size,
                              hipStream_t stream) {
    const float* h     = (const float*)d_in[0];
    const int*   src   = (const int*)d_in[1];
    const int*   dst   = (const int*)d_in[2];
    const float* eps   = (const float*)d_in[3];
    const float* W1    = (const float*)d_in[4];
    const float* b1    = (const float*)d_in[5];
    const float* W2    = (const float*)d_in[6];
    const float* b2    = (const float*)d_in[7];
    const float* gamma = (const float*)d_in[8];
    const float* beta  = (const float*)d_in[9];
    float* out = (float*)d_out;

    const int n = in_sizes[0] / DD;   // 50000
    const int E = in_sizes[1];        // 1600000

    // workspace layout (floats)
    float* ws    = (float*)d_ws;
    float* agg   = ws;                        // n*DD, reused as z2 after GEMM1
    float* z1    = ws + (size_t)n * DD;       // n*DD
    float* stats = ws + (size_t)2 * n * DD;   // 256
    float* scsh  = stats + 256;               // 256
    float* z2    = agg;

    // CSR scratch overlaid on z1 (dead until GEMM1 writes it):
    // deg/cursor/off/ssrc = 3n+1+E ints (~7 MB) << n*DD floats (25.6 MB)
    int* deg    = (int*)z1;
    int* cursor = deg + n;
    int* off    = cursor + n;
    int* ssrc   = off + n + 1;

    hipMemsetAsync(deg, 0, (size_t)n * sizeof(int), stream);
    hipMemsetAsync(stats, 0, 256 * sizeof(float), stream);

    {   // CSR build
        int blocks = (E + 255) / 256;
        hist_kernel<<<blocks, 256, 0, stream>>>(dst, deg, E);
        scan_kernel<<<1, 1024, 0, stream>>>(deg, off, cursor, n);
        fill_kernel<<<blocks, 256, 0, stream>>>(src, dst, cursor, ssrc, E);
    }
    {   // gather (atomic-free aggregation)
        int blocks = (n + 7) / 8;
        gather_kernel<<<blocks, 256, 0, stream>>>(h, off, ssrc, agg, n);
    }
    {   // GEMM1: z1 = relu(((1+eps)h + agg) @ W1 + b1)
        int blocks = (n + 63) / 64;
        gemm_kernel<true, true, false><<<blocks, 256, 0, stream>>>(
            h, agg, eps, W1, b1, z1, nullptr, n);
    }
    {   // GEMM2: z2 = z1 @ W2 + b2, with BN stats
        int blocks = (n + 63) / 64;
        gemm_kernel<false, false, true><<<blocks, 256, 0, stream>>>(
            z1, nullptr, nullptr, W2, b2, z2, stats, n);
    }
    bn_finalize<<<1, 128, 0, stream>>>(stats, gamma, beta, scsh, n);
    {   // apply BN + leaky relu + residual
        int total4 = n * DD / 4;
        int blocks = (total4 + 255) / 256;
        apply_kernel<<<blocks, 256, 0, stream>>>(h, z2, scsh, out, total4);
    }
}